// Round 1
// baseline (63.536 us; speedup 1.0000x reference)
//
#include <hip/hip_runtime.h>

#define D    320
#define D4   80      // float4 per x row
#define DIM1 10
#define DIM2 5
#define WIN  5
#define BR   32      // rows per block tile
#define BLK  256     // threads per block

#if defined(__has_builtin)
#if __has_builtin(__builtin_amdgcn_global_load_lds)
#define USE_GLL 1
#endif
#endif

typedef __attribute__((address_space(3))) void lds_void_t;
typedef const __attribute__((address_space(1))) void gbl_void_t;

// Kernel 1: t = relu(relu(x @ W1^T) @ W2^T + b2), t is [N, 5] in d_ws.
__global__ __launch_bounds__(BLK, 3)
void fcl_t_kernel(const float4* __restrict__ x4,
                  const float4* __restrict__ w1g,
                  const float*  __restrict__ w2,
                  const float*  __restrict__ b2,
                  float*        __restrict__ tout,
                  int Nrows)
{
    // x tile, swizzled layout: slot f = r*80 + i*8 + p' holds
    // x[row0+r], float4 #((p'^(r&7))*10 + i).  Linear LDS dest for global_load_lds,
    // swizzle applied via the per-lane GLOBAL source address (guide rule #21).
    __shared__ float4 xs[BR * D4];    // 2560 float4 = 40 KB
    __shared__ float4 w1s[DIM1 * D4]; // 800 float4 = 12.8 KB  (total 53760 B -> 3 blocks/CU)

    const int tid  = threadIdx.x;
    const int row0 = blockIdx.x * BR;

    // stage W1 linearly (reads later are wave-broadcast, conflict-free)
    for (int f = tid; f < DIM1 * D4; f += BLK)
        w1s[f] = w1g[f];

    // stage x tile
    #pragma unroll
    for (int j = 0; j < (BR * D4) / BLK; ++j) {
        int f  = tid + j * BLK;          // linear LDS float4 slot
        int r  = f / D4;                 // row within tile (magic-mul div)
        int q  = f - r * D4;
        int i  = q >> 3;
        int pp = (q & 7) ^ (r & 7);      // inverse swizzle on the source
        int rg = row0 + r;
        if (rg >= Nrows) rg = Nrows - 1; // clamp: keep load in-bounds (result unused)
        const float4* src = x4 + (size_t)rg * D4 + pp * 10 + i;
#if USE_GLL
        __builtin_amdgcn_global_load_lds((gbl_void_t*)src,
                                         (lds_void_t*)&xs[f],
                                         16, 0, 0);
#else
        xs[f] = *src;
#endif
    }
    __syncthreads();

    const int r  = tid >> 3;   // row within tile (0..31)
    const int p  = tid & 7;    // K-partition (0..7), 40 floats each
    const int px = p ^ (r & 7);

    // this thread's 40 floats of its row: floats [p*40, p*40+40)
    float4 xv[10];
    #pragma unroll
    for (int i = 0; i < 10; ++i)
        xv[i] = xs[r * D4 + i * 8 + px];

    float h[DIM1];
    #pragma unroll
    for (int d = 0; d < DIM1; ++d) {
        float s = 0.f;
        #pragma unroll
        for (int i = 0; i < 10; ++i) {
            float4 w = w1s[d * D4 + p * 10 + i];  // broadcast across the 8 rows
            s += xv[i].x * w.x;
            s += xv[i].y * w.y;
            s += xv[i].z * w.z;
            s += xv[i].w * w.w;
        }
        // reduce across the 8 K-partitions (lane bits 0..2)
        s += __shfl_xor(s, 1);
        s += __shfl_xor(s, 2);
        s += __shfl_xor(s, 4);
        h[d] = fmaxf(s, 0.f);
    }

    const int rowg = row0 + r;
    if (p < DIM2 && rowg < Nrows) {
        float s = b2[p];
        #pragma unroll
        for (int d = 0; d < DIM1; ++d)
            s += h[d] * w2[p * DIM1 + d];
        tout[(size_t)rowg * DIM2 + p] = fmaxf(s, 0.f);
    }
}

// Kernel 2: out[n, j] = t[5n + j - 10] (zero outside [0, 5N)), j in [0,25).
__global__ __launch_bounds__(256)
void gather_win_kernel(const float* __restrict__ t,
                       float*       __restrict__ out,
                       int total,   // N*25
                       int tN5)     // N*5
{
    int i = blockIdx.x * 256 + threadIdx.x;
    int e = i * 4;
    if (e >= total) return;

    unsigned n = (unsigned)e / 25u;      // one magic-div
    int j   = e - (int)n * 25;
    int idx = (int)n * 5 + j - 10;       // t index = 5n + j - 10

    float v[4];
    #pragma unroll
    for (int u = 0; u < 4; ++u) {
        v[u] = ((unsigned)idx < (unsigned)tN5) ? t[idx] : 0.f;
        ++j; ++idx;
        if (j == 25) { j = 0; idx -= 20; }   // next row: 5(n+1)+0-10
    }

    if (e + 4 <= total) {
        *(float4*)(out + e) = make_float4(v[0], v[1], v[2], v[3]);
    } else {
        for (int u = 0; u < total - e; ++u) out[e + u] = v[u];
    }
}

extern "C" void kernel_launch(void* const* d_in, const int* in_sizes, int n_in,
                              void* d_out, int out_size, void* d_ws, size_t ws_size,
                              hipStream_t stream)
{
    const float4* x4 = (const float4*)d_in[0];
    const float4* w1 = (const float4*)d_in[1];
    const float*  w2 = (const float*)d_in[2];
    const float*  b2 = (const float*)d_in[3];

    const int N = in_sizes[0] / D;       // 200000
    float* t   = (float*)d_ws;           // N*5 floats = 4 MB scratch
    float* out = (float*)d_out;

    const int tiles = (N + BR - 1) / BR;
    fcl_t_kernel<<<tiles, BLK, 0, stream>>>(x4, w1, w2, b2, t, N);

    const int total  = N * (DIM2 * WIN); // N*25
    const int total4 = (total + 3) / 4;
    gather_win_kernel<<<(total4 + 255) / 256, 256, 0, stream>>>(t, out, total, N * DIM2);
}